// Round 5
// baseline (348.923 us; speedup 1.0000x reference)
//
#include <hip/hip_runtime.h>

typedef __bf16 bf16;
typedef __bf16 bf16x4 __attribute__((ext_vector_type(4)));
typedef __bf16 bf16x8 __attribute__((ext_vector_type(8)));
typedef float f32x4 __attribute__((ext_vector_type(4)));

#define B_ 128
#define T_ 200
#define V_ 50257
#define H_ 256
#define E_ 128
#define OOV_ 50
#define VO_ 50307          // V + OOV
#define NRG 64             // n-rows per score block
#define NTS 4              // 16-wide n-tiles per score block
#define GSC 786            // score blocks (786*64 = 50304 >= V)
#define PSTR 800           // pg_part row stride
#define PBSTR 50368        // padded bf16 exp-buffer stride (x2B = 100736, 128B-aligned)
#define GPJ 400            // proj blocks

__device__ __forceinline__ float sigmoid_(float x) { return 1.0f / (1.0f + __expf(-x)); }
__device__ __forceinline__ float tanh_(float x) { return 1.0f - 2.0f / (__expf(2.0f * x) + 1.0f); }

// K1: fused front kernel. blocks [0,128): pack Wc fp32 -> bf16 frag order
// [nt(16)][kstep(16)][lane(64)][8]; blocks [128,256): prep (hT, ginT).
__global__ void k_front(const float* Wc_w, bf16* WcPack,
                        const int* step_p, const float* enc, const float* prev,
                        const float* selread, const int* dec, const float* emb,
                        const float* Wi_w, const float* Wi_b,
                        float* hT, float* ginT) {
    if (blockIdx.x < 128) {
        int gid = blockIdx.x * 256 + threadIdx.x;   // 32768 float4s
        int n = gid >> 7;
        int k = (gid & 127) * 4;
        float4 v = *(const float4*)(Wc_w + n * 512 + k);
        int kstep = k >> 5, kin = k & 31;
        int q = kin >> 3, j0 = kin & 7;
        int r = n & 15, nt = n >> 4;
        int lane = q * 16 + r;
        bf16* d = WcPack + (((nt * 16 + kstep) * 64) + lane) * 8 + j0;
        d[0] = (bf16)v.x; d[1] = (bf16)v.y; d[2] = (bf16)v.z; d[3] = (bf16)v.w;
    } else {
        int b = blockIdx.x - 128, t = threadIdx.x;
        int step = step_p[0];
        float h;
        if (step == 0) {
            float acc = Wi_b[t];
            const float* er = enc + (b * T_ + (T_ - 1)) * 512;
            const float* wr = Wi_w + t * 512;
            for (int k = 0; k < 512; ++k) acc += er[k] * wr[k];
            h = acc;
        } else {
            h = prev[b * H_ + t];
        }
        hT[t * B_ + b] = h;
        for (int k = t; k < 512; k += 256)
            ginT[k * B_ + b] = (step == 0) ? 0.0f : selread[b * 512 + k];
        if (t < E_)
            ginT[(512 + t) * B_ + b] = emb[dec[b] * E_ + t];
    }
}

// K2: gi = gru_in @ W_ih^T + b_ih ; gh = h @ W_hh^T + b_hh  (K-split, 768 blocks)
__global__ void k_gemm_gru(const float* W_ih, const float* b_ih,
                           const float* W_hh, const float* b_hh,
                           const float* ginT, const float* hT,
                           float* giT, float* ghT) {
    __shared__ float red[256];
    int rrow = blockIdx.x;            // 0..767
    int t = threadIdx.x;
    int b = t & 127, kh = t >> 7;
    const float* w = W_ih + rrow * 640 + kh * 320;
    const float* g = ginT + (kh * 320) * B_ + b;
    float a0 = 0.f, a1 = 0.f, a2 = 0.f, a3 = 0.f;
#pragma unroll 4
    for (int k = 0; k < 320; k += 4) {
        a0 += w[k]     * g[k * B_];
        a1 += w[k + 1] * g[(k + 1) * B_];
        a2 += w[k + 2] * g[(k + 2) * B_];
        a3 += w[k + 3] * g[(k + 3) * B_];
    }
    const float* w2 = W_hh + rrow * 256 + kh * 128;
    const float* hh = hT + (kh * 128) * B_ + b;
    float c0 = 0.f, c1 = 0.f, c2 = 0.f, c3 = 0.f;
#pragma unroll 4
    for (int k = 0; k < 128; k += 4) {
        c0 += w2[k]     * hh[k * B_];
        c1 += w2[k + 1] * hh[(k + 1) * B_];
        c2 += w2[k + 2] * hh[(k + 2) * B_];
        c3 += w2[k + 3] * hh[(k + 3) * B_];
    }
    red[t] = ((a0 + a1) + (a2 + a3));
    __syncthreads();
    if (kh == 0) giT[rrow * B_ + b] = b_ih[rrow] + red[b] + red[b + 128];
    __syncthreads();
    red[t] = ((c0 + c1) + (c2 + c3));
    __syncthreads();
    if (kh == 0) ghT[rrow * B_ + b] = b_hh[rrow] + red[b] + red[b + 128];
}

// K3: GRU cell -> decode_hidden fp32 (out) + bf16 A-fragment-packed copy
__global__ void k_gru_cell(const float* giT, const float* ghT, const float* hT,
                           float* out_dh, bf16* Apack) {
    int b = blockIdx.x, j = threadIdx.x;
    float ir = giT[j * B_ + b], iz = giT[(256 + j) * B_ + b], in_ = giT[(512 + j) * B_ + b];
    float hr = ghT[j * B_ + b], hz = ghT[(256 + j) * B_ + b], hn = ghT[(512 + j) * B_ + b];
    float hp = hT[j * B_ + b];
    float r = sigmoid_(ir + hr);
    float z = sigmoid_(iz + hz);
    float n = tanh_(in_ + r * hn);
    float h = (1.0f - z) * n + z * hp;
    out_dh[b * H_ + j] = h;
    // Apack[mt(8)][ks(8)][lane(64)][8]: m = mt*16 + (lane&15), k = ks*32 + (lane>>4)*8 + jj
    int mt = b >> 4, rr = b & 15, ks = j >> 5, q = (j >> 3) & 3, jj = j & 7;
    Apack[(((mt * 8 + ks) * 64) + (q * 16 + rr)) * 8 + jj] = (bf16)h;
}

// K4a: score_g. 512 threads / 8 waves per block, each wave owns one 16-row
// m-tile (mt = wave id). Zero LDS; B-fragments global->reg (Wg_w is L3-hot).
// exp output goes to a PADDED bf16 buffer: each block's per-row span is one
// full aligned 128B line -> no partial-line RMW (r4's 38MB-vs-26MB write bloat).
// Grid 786 x 8 waves = 24 waves/CU resident -> 3x the TLP of r4.
__global__ __launch_bounds__(512, 6) void k_score(const bf16* Apack, const float* Wg_w,
                                                  const float* Wg_b,
                                                  bf16* expg, float* pg_part) {
    int tid = threadIdx.x;
    int w = tid >> 6, lane = tid & 63;
    int r = lane & 15, q = lane >> 4;
    int blk = blockIdx.x;
    int n0 = blk * NRG;
    int off[NTS];
#pragma unroll
    for (int nt = 0; nt < NTS; ++nt) {
        int n = n0 + nt * 16 + r;
        off[nt] = ((n < V_) ? n : (V_ - 1)) * 256;
    }
    const float* bp = Wg_w + q * 8;    // per-lane base within row
    f32x4 acc[NTS];
#pragma unroll
    for (int i = 0; i < NTS; ++i) acc[i] = (f32x4){0.f, 0.f, 0.f, 0.f};
#pragma unroll
    for (int ks = 0; ks < 8; ++ks) {
        bf16x8 a = *(const bf16x8*)(Apack + (w * 8 + ks) * 512 + lane * 8);
        bf16x8 bfr[NTS];
#pragma unroll
        for (int nt = 0; nt < NTS; ++nt) {
            float4 va = *(const float4*)(bp + off[nt] + ks * 32);
            float4 vb = *(const float4*)(bp + off[nt] + ks * 32 + 4);
            bfr[nt][0] = (bf16)va.x; bfr[nt][1] = (bf16)va.y;
            bfr[nt][2] = (bf16)va.z; bfr[nt][3] = (bf16)va.w;
            bfr[nt][4] = (bf16)vb.x; bfr[nt][5] = (bf16)vb.y;
            bfr[nt][6] = (bf16)vb.z; bfr[nt][7] = (bf16)vb.w;
        }
#pragma unroll
        for (int nt = 0; nt < NTS; ++nt)
            acc[nt] = __builtin_amdgcn_mfma_f32_16x16x32_bf16(a, bfr[nt], acc[nt], 0, 0, 0);
    }
    // epilogue: exp, bf16 stores into padded buffer, in-register row sums
    float rsum[4] = {0.f, 0.f, 0.f, 0.f};
#pragma unroll
    for (int nt = 0; nt < NTS; ++nt) {
        int n = n0 + nt * 16 + r;
        bool valid = (n < V_);
        float wgb = Wg_b[valid ? n : (V_ - 1)];
#pragma unroll
        for (int rg = 0; rg < 4; ++rg) {
            int row = w * 16 + q * 4 + rg;
            float e = valid ? __expf(acc[nt][rg] + wgb) : 0.0f;
            rsum[rg] += e;
            expg[row * PBSTR + n] = (bf16)e;   // pad region never read
        }
    }
#pragma unroll
    for (int rg = 0; rg < 4; ++rg) {
        float s = rsum[rg];
        s += __shfl_xor(s, 1);
        s += __shfl_xor(s, 2);
        s += __shfl_xor(s, 4);
        s += __shfl_xor(s, 8);
        if (r == 0) {
            int row = w * 16 + q * 4 + rg;
            pg_part[row * PSTR + blk] = s;
        }
    }
}

// K4b: proj + score_c (enc is L3-resident -> fast staging).
__global__ __launch_bounds__(256, 4) void k_proj(const float* enc, const bf16* WcPack,
                                                 const float* Wc_b, const float* dh,
                                                 const int* idxs, float* expc) {
    __shared__ unsigned char smem[34816];
    int tid = threadIdx.x;
    int w = tid >> 6, lane = tid & 63;
    int r = lane & 15, q = lane >> 4;
    int m0 = blockIdx.x * 64;
    bf16* As = (bf16*)smem;                    // 64 rows x 256 k, stride 264
    float* sred = (float*)(smem + 33792);      // 64 x 4
    f32x4 acc[16];
#pragma unroll
    for (int i = 0; i < 16; ++i) acc[i] = (f32x4){0.f, 0.f, 0.f, 0.f};
    for (int half = 0; half < 2; ++half) {
        __syncthreads();
        // two-phase staging: 16 rounds = 2 x (8 loads, 8 cvt+write)
#pragma unroll
        for (int ph = 0; ph < 2; ++ph) {
            float4 tmp[8];
#pragma unroll
            for (int j = 0; j < 8; ++j) {
                int f = (ph * 8 + j) * 256 + tid;
                int row = f >> 6, c4 = f & 63;
                tmp[j] = *(const float4*)(enc + (m0 + row) * 512 + half * 256 + c4 * 4);
            }
#pragma unroll
            for (int j = 0; j < 8; ++j) {
                int f = (ph * 8 + j) * 256 + tid;
                int row = f >> 6, c4 = f & 63;
                bf16x4 o;
                o[0] = (bf16)tmp[j].x; o[1] = (bf16)tmp[j].y;
                o[2] = (bf16)tmp[j].z; o[3] = (bf16)tmp[j].w;
                *(bf16x4*)(As + row * 264 + c4 * 4) = o;
            }
        }
        __syncthreads();
#pragma unroll
        for (int ks = 0; ks < 8; ++ks) {
            int kstep = half * 8 + ks;
            bf16x8 bfr[4];
#pragma unroll
            for (int ntl = 0; ntl < 4; ++ntl)
                bfr[ntl] = *(const bf16x8*)(WcPack + (((w * 4 + ntl) * 16 + kstep) * 64 + lane) * 8);
#pragma unroll
            for (int mt = 0; mt < 4; ++mt) {
                bf16x8 a = *(const bf16x8*)(As + (mt * 16 + r) * 264 + ks * 32 + q * 8);
#pragma unroll
                for (int ntl = 0; ntl < 4; ++ntl)
                    acc[mt * 4 + ntl] = __builtin_amdgcn_mfma_f32_16x16x32_bf16(a, bfr[ntl], acc[mt * 4 + ntl], 0, 0, 0);
            }
        }
    }
#pragma unroll
    for (int mt = 0; mt < 4; ++mt) {
#pragma unroll
        for (int rg = 0; rg < 4; ++rg) {
            int rowl = mt * 16 + q * 4 + rg;
            int row = m0 + rowl;
            int b = row / T_;
            float s = 0.0f;
#pragma unroll
            for (int ntl = 0; ntl < 4; ++ntl) {
                int n = (w * 4 + ntl) * 16 + r;
                float pv = tanh_(acc[mt * 4 + ntl][rg] + Wc_b[n]);
                s += pv * dh[b * H_ + n];
            }
            s += __shfl_xor(s, 1);
            s += __shfl_xor(s, 2);
            s += __shfl_xor(s, 4);
            s += __shfl_xor(s, 8);
            if (r == 0) sred[rowl * 4 + w] = s;
        }
    }
    __syncthreads();
    if (tid < 64) {
        float s = sred[tid * 4] + sred[tid * 4 + 1] + sred[tid * 4 + 2] + sred[tid * 4 + 3];
        int row = m0 + tid;
        int b = row / T_, t = row - b * T_;
        float sc = tanh_(s);
        if (idxs[b * T_ + t] == 0) sc -= 10000.0f;
        expc[row] = __expf(sc);
    }
}

// K5: fused finish. 2 blocks per batch row (hf = column half). Each block:
// computes inv (redundant, cheap), writes normalized out_prob for its half
// from the padded bf16 exp buffer (+1e-4 OOV pad), computes its 256 dims of
// selective_read, then (after fence) atomicAdds the normalized copy-probs
// into its own half. k_norm eliminated; out_prob written exactly once + atomics.
__global__ void k_finish(const float* pg_part, const float* expc_, const int* idxs,
                         const int* dec, const float* enc, const bf16* expg,
                         float* out_prob, float* out_sel) {
    __shared__ float red[256];
    __shared__ float cf[256];
    int b = blockIdx.x >> 1, hf = blockIdx.x & 1;
    int t = threadIdx.x;
    float s = 0.0f;
    for (int i = t; i < GSC; i += 256) s += pg_part[b * PSTR + i];
    if (t < T_) s += expc_[b * T_ + t];
    red[t] = s;
    __syncthreads();
    for (int k = 128; k > 0; k >>= 1) {
        if (t < k) red[t] += red[t + k];
        __syncthreads();
    }
    float iv = 1.0f / red[0];
    __syncthreads();
    int d = dec[b];
    float ec = 0.0f;
    int ix = -1;
    int m = 0;
    if (t < T_) {
        ix = idxs[b * T_ + t];
        ec = expc_[b * T_ + t];
        m = (ix == d) ? 1 : 0;
    }
    cf[t] = m ? ec * iv : 0.0f;
    red[t] = m ? 1.0f : 0.0f;
    __syncthreads();
    for (int k = 128; k > 0; k >>= 1) {
        if (t < k) red[t] += red[t + k];
        __syncthreads();
    }
    float tot = red[0];
    float scale = (tot > 1.0f) ? 1.0f / tot : 1.0f;
    // selective_read: this block covers dim = t + hf*256
    int dim = t + hf * 256;
    float a0 = 0.0f;
    for (int tt = 0; tt < T_; ++tt) {
        float c = cf[tt];
        if (c != 0.0f) a0 += c * scale * enc[(b * T_ + tt) * 512 + dim];
    }
    out_sel[b * 512 + dim] = a0;
    // write normalized base values for own column half (single writer)
    const int halfc = (VO_ + 1) / 2;          // 25154
    int cl0 = hf * halfc;
    int cl1 = (cl0 + halfc < VO_) ? cl0 + halfc : VO_;
    int base = b * VO_;
    const bf16* eg = expg + b * PBSTR;
    int s0 = base + cl0, s1 = base + cl1;
    int a4 = (s0 + 3) & ~3;
    int b4 = s1 & ~3;
    if (t < a4 - s0) {
        int i = s0 + t;
        int col = i - base;
        out_prob[i] = (col < V_) ? (float)eg[col] * iv : 1e-4f;
    }
    if (t < s1 - b4) {
        int i = b4 + t;
        int col = i - base;
        out_prob[i] = (col < V_) ? (float)eg[col] * iv : 1e-4f;
    }
    for (int i4 = a4 / 4 + t; i4 < b4 / 4; i4 += 256) {
        int c0 = i4 * 4 - base;
        float o[4];
#pragma unroll
        for (int c = 0; c < 4; ++c) {
            int col = c0 + c;
            o[c] = (col < V_) ? (float)eg[col] * iv : 1e-4f;
        }
        *(float4*)(out_prob + i4 * 4) = make_float4(o[0], o[1], o[2], o[3]);
    }
    // scatter normalized copy-probs on top (own half only; base writes visible)
    __threadfence();
    __syncthreads();
    if (t < T_ && ix >= cl0 && ix < cl1)
        atomicAdd(&out_prob[base + ix], ec * iv);
}

extern "C" void kernel_launch(void* const* d_in, const int* in_sizes, int n_in,
                              void* d_out, int out_size, void* d_ws, size_t ws_size,
                              hipStream_t stream) {
    const int*   dec     = (const int*)d_in[0];
    const float* enc     = (const float*)d_in[1];
    const int*   idxs    = (const int*)d_in[2];
    const float* prev    = (const float*)d_in[3];
    const float* selread = (const float*)d_in[4];
    const int*   step_p  = (const int*)d_in[5];
    const float* emb     = (const float*)d_in[6];
    const float* W_ih    = (const float*)d_in[7];
    const float* W_hh    = (const float*)d_in[8];
    const float* b_ih    = (const float*)d_in[9];
    const float* b_hh    = (const float*)d_in[10];
    const float* Wi_w    = (const float*)d_in[11];
    const float* Wi_b    = (const float*)d_in[12];
    const float* Wg_w    = (const float*)d_in[13];
    const float* Wg_b    = (const float*)d_in[14];
    const float* Wc_w    = (const float*)d_in[15];
    const float* Wc_b    = (const float*)d_in[16];

    float* ws     = (float*)d_ws;
    float* hT     = ws;                 // 32768
    float* ginT   = ws + 32768;         // 81920
    float* giT    = ws + 114688;        // 98304
    float* ghT    = ws + 212992;        // 98304
    float* expc   = ws + 311552;        // 25600
    float* pgp    = ws + 337152;        // 128*800 = 102400
    bf16*  Apack  = (bf16*)(ws + 741376);   // 32768 bf16 (64KB)
    bf16*  WcPack = (bf16*)(ws + 757760);   // 131072 bf16 (256KB)
    bf16*  expg   = (bf16*)(ws + 823296);   // 128*50368 bf16 (12.9MB, padded)

    float* out      = (float*)d_out;
    float* out_prob = out;                       // 128*50307
    float* out_dh   = out + 6439296;             // 128*256
    float* out_sel  = out + 6439296 + 32768;     // 128*512

    k_front<<<256, 256, 0, stream>>>(Wc_w, WcPack, step_p, enc, prev, selread, dec,
                                     emb, Wi_w, Wi_b, hT, ginT);
    k_gemm_gru<<<768, 256, 0, stream>>>(W_ih, b_ih, W_hh, b_hh, ginT, hT, giT, ghT);
    k_gru_cell<<<B_, 256, 0, stream>>>(giT, ghT, hT, out_dh, Apack);
    k_proj<<<GPJ, 256, 0, stream>>>(enc, WcPack, Wc_b, out_dh, idxs, expc);
    k_score<<<GSC, 512, 0, stream>>>(Apack, Wg_w, Wg_b, expg, pgp);
    k_finish<<<256, 256, 0, stream>>>(pgp, expc, idxs, dec, enc, expg, out_prob, out_sel);
}

// Round 6
// 311.224 us; speedup vs baseline: 1.1211x; 1.1211x over previous
//
#include <hip/hip_runtime.h>

typedef __bf16 bf16;
typedef __bf16 bf16x4 __attribute__((ext_vector_type(4)));
typedef __bf16 bf16x8 __attribute__((ext_vector_type(8)));
typedef float f32x4 __attribute__((ext_vector_type(4)));

#define B_ 128
#define T_ 200
#define V_ 50257
#define H_ 256
#define E_ 128
#define OOV_ 50
#define VO_ 50307          // V + OOV
#define NRG 64             // n-rows per score block
#define NTS 4              // 16-wide n-tiles per score block
#define GSC 786            // score blocks (786*64 = 50304 >= V)
#define NROWP 50304        // padded Wg rows (GSC*64)
#define PSTR 800           // pg_part row stride
#define PBSTR 50368        // padded bf16 exp-buffer stride (x2B = 100736, 128B-aligned)
#define GPJ 400            // proj blocks
#define GWPACK 12576       // Wg-pack blocks: 50304*64 float4s / 256

__device__ __forceinline__ float sigmoid_(float x) { return 1.0f / (1.0f + __expf(-x)); }
__device__ __forceinline__ float tanh_(float x) { return 1.0f - 2.0f / (__expf(2.0f * x) + 1.0f); }

// K1: fused front kernel.
//  blocks [0,128):        pack Wc fp32 -> bf16 frag order [nt16][ks16][lane64][8]
//  blocks [128,256):      prep (hT, ginT)
//  blocks [256,256+GWPACK): pack Wg fp32 -> bf16 frag order [nt3144][ks8][lane64][8]
//    (WgPack lives in the out_prob region: dead until k_finish overwrites it)
__global__ void k_front(const float* Wc_w, bf16* WcPack,
                        const int* step_p, const float* enc, const float* prev,
                        const float* selread, const int* dec, const float* emb,
                        const float* Wi_w, const float* Wi_b,
                        float* hT, float* ginT,
                        const float* Wg_w, bf16* WgPack) {
    if (blockIdx.x < 128) {
        int gid = blockIdx.x * 256 + threadIdx.x;   // 32768 float4s
        int n = gid >> 7;
        int k = (gid & 127) * 4;
        float4 v = *(const float4*)(Wc_w + n * 512 + k);
        int kstep = k >> 5, kin = k & 31;
        int q = kin >> 3, j0 = kin & 7;
        int r = n & 15, nt = n >> 4;
        int lane = q * 16 + r;
        bf16* d = WcPack + (((nt * 16 + kstep) * 64) + lane) * 8 + j0;
        d[0] = (bf16)v.x; d[1] = (bf16)v.y; d[2] = (bf16)v.z; d[3] = (bf16)v.w;
    } else if (blockIdx.x < 256) {
        int b = blockIdx.x - 128, t = threadIdx.x;
        int step = step_p[0];
        float h;
        if (step == 0) {
            float acc = Wi_b[t];
            const float* er = enc + (b * T_ + (T_ - 1)) * 512;
            const float* wr = Wi_w + t * 512;
            for (int k = 0; k < 512; ++k) acc += er[k] * wr[k];
            h = acc;
        } else {
            h = prev[b * H_ + t];
        }
        hT[t * B_ + b] = h;
        for (int k = t; k < 512; k += 256)
            ginT[k * B_ + b] = (step == 0) ? 0.0f : selread[b * 512 + k];
        if (t < E_)
            ginT[(512 + t) * B_ + b] = emb[dec[b] * E_ + t];
    } else {
        // Wg pack: gid over NROWP x 64 float4s; pad rows (>= V_) are zeroed.
        int gid = (blockIdx.x - 256) * 256 + threadIdx.x;
        int row = gid >> 6;
        int k = (gid & 63) * 4;
        float4 v = (row < V_) ? *(const float4*)(Wg_w + row * 256 + k)
                              : float4{0.f, 0.f, 0.f, 0.f};
        int nt = row >> 4, r = row & 15;
        int ks = k >> 5, kin = k & 31;
        int q = kin >> 3, j0 = kin & 7;
        int lane = q * 16 + r;
        bf16* d = WgPack + (((nt * 8 + ks) * 64) + lane) * 8 + j0;
        d[0] = (bf16)v.x; d[1] = (bf16)v.y; d[2] = (bf16)v.z; d[3] = (bf16)v.w;
    }
}

// K2: gi = gru_in @ W_ih^T + b_ih ; gh = h @ W_hh^T + b_hh  (K-split, 768 blocks)
__global__ void k_gemm_gru(const float* W_ih, const float* b_ih,
                           const float* W_hh, const float* b_hh,
                           const float* ginT, const float* hT,
                           float* giT, float* ghT) {
    __shared__ float red[256];
    int rrow = blockIdx.x;            // 0..767
    int t = threadIdx.x;
    int b = t & 127, kh = t >> 7;
    const float* w = W_ih + rrow * 640 + kh * 320;
    const float* g = ginT + (kh * 320) * B_ + b;
    float a0 = 0.f, a1 = 0.f, a2 = 0.f, a3 = 0.f;
#pragma unroll 4
    for (int k = 0; k < 320; k += 4) {
        a0 += w[k]     * g[k * B_];
        a1 += w[k + 1] * g[(k + 1) * B_];
        a2 += w[k + 2] * g[(k + 2) * B_];
        a3 += w[k + 3] * g[(k + 3) * B_];
    }
    const float* w2 = W_hh + rrow * 256 + kh * 128;
    const float* hh = hT + (kh * 128) * B_ + b;
    float c0 = 0.f, c1 = 0.f, c2 = 0.f, c3 = 0.f;
#pragma unroll 4
    for (int k = 0; k < 128; k += 4) {
        c0 += w2[k]     * hh[k * B_];
        c1 += w2[k + 1] * hh[(k + 1) * B_];
        c2 += w2[k + 2] * hh[(k + 2) * B_];
        c3 += w2[k + 3] * hh[(k + 3) * B_];
    }
    red[t] = ((a0 + a1) + (a2 + a3));
    __syncthreads();
    if (kh == 0) giT[rrow * B_ + b] = b_ih[rrow] + red[b] + red[b + 128];
    __syncthreads();
    red[t] = ((c0 + c1) + (c2 + c3));
    __syncthreads();
    if (kh == 0) ghT[rrow * B_ + b] = b_hh[rrow] + red[b] + red[b + 128];
}

// K3: GRU cell -> decode_hidden fp32 (out) + bf16 A-fragment-packed copy
__global__ void k_gru_cell(const float* giT, const float* ghT, const float* hT,
                           float* out_dh, bf16* Apack) {
    int b = blockIdx.x, j = threadIdx.x;
    float ir = giT[j * B_ + b], iz = giT[(256 + j) * B_ + b], in_ = giT[(512 + j) * B_ + b];
    float hr = ghT[j * B_ + b], hz = ghT[(256 + j) * B_ + b], hn = ghT[(512 + j) * B_ + b];
    float hp = hT[j * B_ + b];
    float r = sigmoid_(ir + hr);
    float z = sigmoid_(iz + hz);
    float n = tanh_(in_ + r * hn);
    float h = (1.0f - z) * n + z * hp;
    out_dh[b * H_ + j] = h;
    // Apack[mt(8)][ks(8)][lane(64)][8]: m = mt*16 + (lane&15), k = ks*32 + (lane>>4)*8 + jj
    int mt = b >> 4, rr = b & 15, ks = j >> 5, q = (j >> 3) & 3, jj = j & 7;
    Apack[(((mt * 8 + ks) * 64) + (q * 16 + rr)) * 8 + jj] = (bf16)h;
}

// K4a: score_g. 512 threads / 8 waves, wave w owns m-tile w. B-fragments are
// DIRECT bf16x8 loads from fragment-ordered WgPack (1KB coalesced per load,
// load IS the MFMA operand -> no cvt between load and use, so the compiler
// batches loads instead of r5's serial load->cvt chains at VGPR=36).
// __launch_bounds__(512,2) gives a 256-VGPR budget to hold loads in flight.
__global__ __launch_bounds__(512, 2) void k_score(const bf16* Apack, const bf16* WgPack,
                                                  const float* Wg_b,
                                                  bf16* expg, float* pg_part) {
    int tid = threadIdx.x;
    int w = tid >> 6, lane = tid & 63;
    int r = lane & 15, q = lane >> 4;
    int blk = blockIdx.x;
    int n0 = blk * NRG;
    const bf16* bbase = WgPack + (size_t)(blk * NTS * 8) * 512 + lane * 8;
    const bf16* abase = Apack + (w * 8) * 512 + lane * 8;
    f32x4 acc[NTS];
#pragma unroll
    for (int i = 0; i < NTS; ++i) acc[i] = (f32x4){0.f, 0.f, 0.f, 0.f};
#pragma unroll
    for (int ks = 0; ks < 8; ++ks) {
        bf16x8 a = *(const bf16x8*)(abase + ks * 512);
#pragma unroll
        for (int nt = 0; nt < NTS; ++nt) {
            bf16x8 bfr = *(const bf16x8*)(bbase + (nt * 8 + ks) * 512);
            acc[nt] = __builtin_amdgcn_mfma_f32_16x16x32_bf16(a, bfr, acc[nt], 0, 0, 0);
        }
    }
    // epilogue: exp, bf16 stores into padded buffer, in-register row sums
    float rsum[4] = {0.f, 0.f, 0.f, 0.f};
#pragma unroll
    for (int nt = 0; nt < NTS; ++nt) {
        int n = n0 + nt * 16 + r;
        bool valid = (n < V_);
        float wgb = Wg_b[valid ? n : (V_ - 1)];
#pragma unroll
        for (int rg = 0; rg < 4; ++rg) {
            int row = w * 16 + q * 4 + rg;
            float e = valid ? __expf(acc[nt][rg] + wgb) : 0.0f;
            rsum[rg] += e;
            expg[row * PBSTR + n] = (bf16)e;   // pad region never read
        }
    }
#pragma unroll
    for (int rg = 0; rg < 4; ++rg) {
        float s = rsum[rg];
        s += __shfl_xor(s, 1);
        s += __shfl_xor(s, 2);
        s += __shfl_xor(s, 4);
        s += __shfl_xor(s, 8);
        if (r == 0) {
            int row = w * 16 + q * 4 + rg;
            pg_part[row * PSTR + blk] = s;
        }
    }
}

// K4b: proj + score_c (enc is L3-resident -> fast staging).
__global__ __launch_bounds__(256, 4) void k_proj(const float* enc, const bf16* WcPack,
                                                 const float* Wc_b, const float* dh,
                                                 const int* idxs, float* expc) {
    __shared__ unsigned char smem[34816];
    int tid = threadIdx.x;
    int w = tid >> 6, lane = tid & 63;
    int r = lane & 15, q = lane >> 4;
    int m0 = blockIdx.x * 64;
    bf16* As = (bf16*)smem;                    // 64 rows x 256 k, stride 264
    float* sred = (float*)(smem + 33792);      // 64 x 4
    f32x4 acc[16];
#pragma unroll
    for (int i = 0; i < 16; ++i) acc[i] = (f32x4){0.f, 0.f, 0.f, 0.f};
    for (int half = 0; half < 2; ++half) {
        __syncthreads();
        // two-phase staging: 16 rounds = 2 x (8 loads, 8 cvt+write)
#pragma unroll
        for (int ph = 0; ph < 2; ++ph) {
            float4 tmp[8];
#pragma unroll
            for (int j = 0; j < 8; ++j) {
                int f = (ph * 8 + j) * 256 + tid;
                int row = f >> 6, c4 = f & 63;
                tmp[j] = *(const float4*)(enc + (m0 + row) * 512 + half * 256 + c4 * 4);
            }
#pragma unroll
            for (int j = 0; j < 8; ++j) {
                int f = (ph * 8 + j) * 256 + tid;
                int row = f >> 6, c4 = f & 63;
                bf16x4 o;
                o[0] = (bf16)tmp[j].x; o[1] = (bf16)tmp[j].y;
                o[2] = (bf16)tmp[j].z; o[3] = (bf16)tmp[j].w;
                *(bf16x4*)(As + row * 264 + c4 * 4) = o;
            }
        }
        __syncthreads();
#pragma unroll
        for (int ks = 0; ks < 8; ++ks) {
            int kstep = half * 8 + ks;
            bf16x8 bfr[4];
#pragma unroll
            for (int ntl = 0; ntl < 4; ++ntl)
                bfr[ntl] = *(const bf16x8*)(WcPack + (((w * 4 + ntl) * 16 + kstep) * 64 + lane) * 8);
#pragma unroll
            for (int mt = 0; mt < 4; ++mt) {
                bf16x8 a = *(const bf16x8*)(As + (mt * 16 + r) * 264 + ks * 32 + q * 8);
#pragma unroll
                for (int ntl = 0; ntl < 4; ++ntl)
                    acc[mt * 4 + ntl] = __builtin_amdgcn_mfma_f32_16x16x32_bf16(a, bfr[ntl], acc[mt * 4 + ntl], 0, 0, 0);
            }
        }
    }
#pragma unroll
    for (int mt = 0; mt < 4; ++mt) {
#pragma unroll
        for (int rg = 0; rg < 4; ++rg) {
            int rowl = mt * 16 + q * 4 + rg;
            int row = m0 + rowl;
            int b = row / T_;
            float s = 0.0f;
#pragma unroll
            for (int ntl = 0; ntl < 4; ++ntl) {
                int n = (w * 4 + ntl) * 16 + r;
                float pv = tanh_(acc[mt * 4 + ntl][rg] + Wc_b[n]);
                s += pv * dh[b * H_ + n];
            }
            s += __shfl_xor(s, 1);
            s += __shfl_xor(s, 2);
            s += __shfl_xor(s, 4);
            s += __shfl_xor(s, 8);
            if (r == 0) sred[rowl * 4 + w] = s;
        }
    }
    __syncthreads();
    if (tid < 64) {
        float s = sred[tid * 4] + sred[tid * 4 + 1] + sred[tid * 4 + 2] + sred[tid * 4 + 3];
        int row = m0 + tid;
        int b = row / T_, t = row - b * T_;
        float sc = tanh_(s);
        if (idxs[b * T_ + t] == 0) sc -= 10000.0f;
        expc[row] = __expf(sc);
    }
}

// K5: fused finish. 2 blocks per batch row (hf = column half). Normalized
// out_prob written from padded bf16 exp buffer with VECTORIZED bf16x4 reads
// (r5 used scalar bf16 loads -> 2.5x penalty), then fence + atomic scatter of
// normalized copy-probs into own half; selective_read as before.
__global__ void k_finish(const float* pg_part, const float* expc_, const int* idxs,
                         const int* dec, const float* enc, const bf16* expg,
                         float* out_prob, float* out_sel) {
    __shared__ float red[256];
    __shared__ float cf[256];
    int b = blockIdx.x >> 1, hf = blockIdx.x & 1;
    int t = threadIdx.x;
    float s = 0.0f;
    for (int i = t; i < GSC; i += 256) s += pg_part[b * PSTR + i];
    if (t < T_) s += expc_[b * T_ + t];
    red[t] = s;
    __syncthreads();
    for (int k = 128; k > 0; k >>= 1) {
        if (t < k) red[t] += red[t + k];
        __syncthreads();
    }
    float iv = 1.0f / red[0];
    __syncthreads();
    int d = dec[b];
    float ec = 0.0f;
    int ix = -1;
    int m = 0;
    if (t < T_) {
        ix = idxs[b * T_ + t];
        ec = expc_[b * T_ + t];
        m = (ix == d) ? 1 : 0;
    }
    cf[t] = m ? ec * iv : 0.0f;
    red[t] = m ? 1.0f : 0.0f;
    __syncthreads();
    for (int k = 128; k > 0; k >>= 1) {
        if (t < k) red[t] += red[t + k];
        __syncthreads();
    }
    float tot = red[0];
    float scale = (tot > 1.0f) ? 1.0f / tot : 1.0f;
    // selective_read: this block covers dim = t + hf*256
    int dim = t + hf * 256;
    float a0 = 0.0f;
    for (int tt = 0; tt < T_; ++tt) {
        float c = cf[tt];
        if (c != 0.0f) a0 += c * scale * enc[(b * T_ + tt) * 512 + dim];
    }
    out_sel[b * 512 + dim] = a0;
    // write normalized base values for own column half (single writer).
    // Column-aligned bf16x4 reads (8B aligned), scalar coalesced fp32 stores.
    const int halfc = (VO_ + 1) / 2;          // 25154
    int cl0 = hf * halfc;
    int cl1 = (cl0 + halfc < VO_) ? cl0 + halfc : VO_;
    int base = b * VO_;
    const bf16* eg = expg + b * PBSTR;
    int c0a = (cl0 + 3) & ~3;                 // first 4-aligned col
    int c1a = cl1 & ~3;                       // last 4-aligned end
    if (t < c0a - cl0) {
        int col = cl0 + t;
        out_prob[base + col] = (col < V_) ? (float)eg[col] * iv : 1e-4f;
    }
    if (t < cl1 - c1a) {
        int col = c1a + t;
        out_prob[base + col] = (col < V_) ? (float)eg[col] * iv : 1e-4f;
    }
    for (int col = c0a + t * 4; col < c1a; col += 256 * 4) {
        bf16x4 ev = *(const bf16x4*)(eg + col);
#pragma unroll
        for (int c = 0; c < 4; ++c) {
            int cc = col + c;
            out_prob[base + cc] = (cc < V_) ? (float)ev[c] * iv : 1e-4f;
        }
    }
    // scatter normalized copy-probs on top (own half only; base writes visible)
    __threadfence();
    __syncthreads();
    if (t < T_ && ix >= cl0 && ix < cl1)
        atomicAdd(&out_prob[base + ix], ec * iv);
}

extern "C" void kernel_launch(void* const* d_in, const int* in_sizes, int n_in,
                              void* d_out, int out_size, void* d_ws, size_t ws_size,
                              hipStream_t stream) {
    const int*   dec     = (const int*)d_in[0];
    const float* enc     = (const float*)d_in[1];
    const int*   idxs    = (const int*)d_in[2];
    const float* prev    = (const float*)d_in[3];
    const float* selread = (const float*)d_in[4];
    const int*   step_p  = (const int*)d_in[5];
    const float* emb     = (const float*)d_in[6];
    const float* W_ih    = (const float*)d_in[7];
    const float* W_hh    = (const float*)d_in[8];
    const float* b_ih    = (const float*)d_in[9];
    const float* b_hh    = (const float*)d_in[10];
    const float* Wi_w    = (const float*)d_in[11];
    const float* Wi_b    = (const float*)d_in[12];
    const float* Wg_w    = (const float*)d_in[13];
    const float* Wg_b    = (const float*)d_in[14];
    const float* Wc_w    = (const float*)d_in[15];
    const float* Wc_b    = (const float*)d_in[16];

    float* ws     = (float*)d_ws;
    float* hT     = ws;                 // 32768
    float* ginT   = ws + 32768;         // 81920
    float* giT    = ws + 114688;        // 98304
    float* ghT    = ws + 212992;        // 98304
    float* expc   = ws + 311552;        // 25600
    float* pgp    = ws + 337152;        // 128*800 = 102400
    bf16*  Apack  = (bf16*)(ws + 741376);   // 32768 bf16 (64KB)
    bf16*  WcPack = (bf16*)(ws + 757760);   // 131072 bf16 (256KB)
    bf16*  expg   = (bf16*)(ws + 823296);   // 128*50368 bf16 (12.9MB, padded)

    float* out      = (float*)d_out;
    float* out_prob = out;                       // 128*50307
    float* out_dh   = out + 6439296;             // 128*256
    float* out_sel  = out + 6439296 + 32768;     // 128*512
    // WgPack scratch aliases out_prob: 50304*256 bf16 = 6,438,912 floats
    // <= 6,439,296 (out_prob size). Dead once k_finish overwrites out_prob.
    bf16*  WgPack   = (bf16*)out;

    k_front<<<256 + GWPACK, 256, 0, stream>>>(Wc_w, WcPack, step_p, enc, prev, selread,
                                              dec, emb, Wi_w, Wi_b, hT, ginT,
                                              Wg_w, WgPack);
    k_gemm_gru<<<768, 256, 0, stream>>>(W_ih, b_ih, W_hh, b_hh, ginT, hT, giT, ghT);
    k_gru_cell<<<B_, 256, 0, stream>>>(giT, ghT, hT, out_dh, Apack);
    k_proj<<<GPJ, 256, 0, stream>>>(enc, WcPack, Wc_b, out_dh, idxs, expc);
    k_score<<<GSC, 512, 0, stream>>>(Apack, WgPack, Wg_b, expg, pgp);
    k_finish<<<256, 256, 0, stream>>>(pgp, expc, idxs, dec, enc, expg, out_prob, out_sel);
}

// Round 7
// 283.504 us; speedup vs baseline: 1.2308x; 1.0978x over previous
//
#include <hip/hip_runtime.h>

typedef __bf16 bf16;
typedef __bf16 bf16x4 __attribute__((ext_vector_type(4)));
typedef __bf16 bf16x8 __attribute__((ext_vector_type(8)));
typedef float f32x4 __attribute__((ext_vector_type(4)));

#define B_ 128
#define T_ 200
#define V_ 50257
#define H_ 256
#define E_ 128
#define OOV_ 50
#define VO_ 50307          // V + OOV
#define NRG 64             // n-rows per score block
#define NTS 4              // 16-wide n-tiles per score block
#define GSC 786            // score blocks (786*64 = 50304 >= V)
#define NROWP 50304        // padded Wg rows (GSC*64)
#define PSTR 800           // pg_part row stride
#define PBSTR 50368        // padded bf16 exp-buffer stride (x2B = 100736, 128B-aligned)
#define GPJ 400            // proj blocks
#define GWPACK 12576       // Wg-pack blocks: 50304*64 float4s / 256

__device__ __forceinline__ float sigmoid_(float x) { return 1.0f / (1.0f + __expf(-x)); }
__device__ __forceinline__ float tanh_(float x) { return 1.0f - 2.0f / (__expf(2.0f * x) + 1.0f); }

// K1: fused front kernel.
//  blocks [0,128):        pack Wc fp32 -> bf16 frag order [nt16][ks16][lane64][8]
//  blocks [128,256):      prep (hT, ginT)
//  blocks [256,256+GWPACK): pack Wg fp32 -> bf16 frag order [nt3144][ks8][lane64][8]
//    (WgPack lives in the out_prob region: dead until k_normwrite overwrites it)
__global__ void k_front(const float* Wc_w, bf16* WcPack,
                        const int* step_p, const float* enc, const float* prev,
                        const float* selread, const int* dec, const float* emb,
                        const float* Wi_w, const float* Wi_b,
                        float* hT, float* ginT,
                        const float* Wg_w, bf16* WgPack) {
    if (blockIdx.x < 128) {
        int gid = blockIdx.x * 256 + threadIdx.x;   // 32768 float4s
        int n = gid >> 7;
        int k = (gid & 127) * 4;
        float4 v = *(const float4*)(Wc_w + n * 512 + k);
        int kstep = k >> 5, kin = k & 31;
        int q = kin >> 3, j0 = kin & 7;
        int r = n & 15, nt = n >> 4;
        int lane = q * 16 + r;
        bf16* d = WcPack + (((nt * 16 + kstep) * 64) + lane) * 8 + j0;
        d[0] = (bf16)v.x; d[1] = (bf16)v.y; d[2] = (bf16)v.z; d[3] = (bf16)v.w;
    } else if (blockIdx.x < 256) {
        int b = blockIdx.x - 128, t = threadIdx.x;
        int step = step_p[0];
        float h;
        if (step == 0) {
            float acc = Wi_b[t];
            const float* er = enc + (b * T_ + (T_ - 1)) * 512;
            const float* wr = Wi_w + t * 512;
            for (int k = 0; k < 512; ++k) acc += er[k] * wr[k];
            h = acc;
        } else {
            h = prev[b * H_ + t];
        }
        hT[t * B_ + b] = h;
        for (int k = t; k < 512; k += 256)
            ginT[k * B_ + b] = (step == 0) ? 0.0f : selread[b * 512 + k];
        if (t < E_)
            ginT[(512 + t) * B_ + b] = emb[dec[b] * E_ + t];
    } else {
        // Wg pack: gid over NROWP x 64 float4s; pad rows (>= V_) are zeroed.
        int gid = (blockIdx.x - 256) * 256 + threadIdx.x;
        int row = gid >> 6;
        int k = (gid & 63) * 4;
        float4 v = (row < V_) ? *(const float4*)(Wg_w + row * 256 + k)
                              : float4{0.f, 0.f, 0.f, 0.f};
        int nt = row >> 4, r = row & 15;
        int ks = k >> 5, kin = k & 31;
        int q = kin >> 3, j0 = kin & 7;
        int lane = q * 16 + r;
        bf16* d = WgPack + (((nt * 8 + ks) * 64) + lane) * 8 + j0;
        d[0] = (bf16)v.x; d[1] = (bf16)v.y; d[2] = (bf16)v.z; d[3] = (bf16)v.w;
    }
}

// K2: gi = gru_in @ W_ih^T + b_ih ; gh = h @ W_hh^T + b_hh  (K-split, 768 blocks)
__global__ void k_gemm_gru(const float* W_ih, const float* b_ih,
                           const float* W_hh, const float* b_hh,
                           const float* ginT, const float* hT,
                           float* giT, float* ghT) {
    __shared__ float red[256];
    int rrow = blockIdx.x;            // 0..767
    int t = threadIdx.x;
    int b = t & 127, kh = t >> 7;
    const float* w = W_ih + rrow * 640 + kh * 320;
    const float* g = ginT + (kh * 320) * B_ + b;
    float a0 = 0.f, a1 = 0.f, a2 = 0.f, a3 = 0.f;
#pragma unroll 4
    for (int k = 0; k < 320; k += 4) {
        a0 += w[k]     * g[k * B_];
        a1 += w[k + 1] * g[(k + 1) * B_];
        a2 += w[k + 2] * g[(k + 2) * B_];
        a3 += w[k + 3] * g[(k + 3) * B_];
    }
    const float* w2 = W_hh + rrow * 256 + kh * 128;
    const float* hh = hT + (kh * 128) * B_ + b;
    float c0 = 0.f, c1 = 0.f, c2 = 0.f, c3 = 0.f;
#pragma unroll 4
    for (int k = 0; k < 128; k += 4) {
        c0 += w2[k]     * hh[k * B_];
        c1 += w2[k + 1] * hh[(k + 1) * B_];
        c2 += w2[k + 2] * hh[(k + 2) * B_];
        c3 += w2[k + 3] * hh[(k + 3) * B_];
    }
    red[t] = ((a0 + a1) + (a2 + a3));
    __syncthreads();
    if (kh == 0) giT[rrow * B_ + b] = b_ih[rrow] + red[b] + red[b + 128];
    __syncthreads();
    red[t] = ((c0 + c1) + (c2 + c3));
    __syncthreads();
    if (kh == 0) ghT[rrow * B_ + b] = b_hh[rrow] + red[b] + red[b + 128];
}

// K3: GRU cell -> decode_hidden fp32 (out) + bf16 A-fragment-packed copy
__global__ void k_gru_cell(const float* giT, const float* ghT, const float* hT,
                           float* out_dh, bf16* Apack) {
    int b = blockIdx.x, j = threadIdx.x;
    float ir = giT[j * B_ + b], iz = giT[(256 + j) * B_ + b], in_ = giT[(512 + j) * B_ + b];
    float hr = ghT[j * B_ + b], hz = ghT[(256 + j) * B_ + b], hn = ghT[(512 + j) * B_ + b];
    float hp = hT[j * B_ + b];
    float r = sigmoid_(ir + hr);
    float z = sigmoid_(iz + hz);
    float n = tanh_(in_ + r * hn);
    float h = (1.0f - z) * n + z * hp;
    out_dh[b * H_ + j] = h;
    // Apack[mt(8)][ks(8)][lane(64)][8]: m = mt*16 + (lane&15), k = ks*32 + (lane>>4)*8 + jj
    int mt = b >> 4, rr = b & 15, ks = j >> 5, q = (j >> 3) & 3, jj = j & 7;
    Apack[(((mt * 8 + ks) * 64) + (q * 16 + rr)) * 8 + jj] = (bf16)h;
}

// K4a: score_g. 512 threads / 8 waves, wave w owns m-tile w. B-fragments are
// DIRECT bf16x8 loads from fragment-ordered WgPack (load IS the MFMA operand).
__global__ __launch_bounds__(512, 2) void k_score(const bf16* Apack, const bf16* WgPack,
                                                  const float* Wg_b,
                                                  bf16* expg, float* pg_part) {
    int tid = threadIdx.x;
    int w = tid >> 6, lane = tid & 63;
    int r = lane & 15, q = lane >> 4;
    int blk = blockIdx.x;
    int n0 = blk * NRG;
    const bf16* bbase = WgPack + (size_t)(blk * NTS * 8) * 512 + lane * 8;
    const bf16* abase = Apack + (w * 8) * 512 + lane * 8;
    f32x4 acc[NTS];
#pragma unroll
    for (int i = 0; i < NTS; ++i) acc[i] = (f32x4){0.f, 0.f, 0.f, 0.f};
#pragma unroll
    for (int ks = 0; ks < 8; ++ks) {
        bf16x8 a = *(const bf16x8*)(abase + ks * 512);
#pragma unroll
        for (int nt = 0; nt < NTS; ++nt) {
            bf16x8 bfr = *(const bf16x8*)(bbase + (nt * 8 + ks) * 512);
            acc[nt] = __builtin_amdgcn_mfma_f32_16x16x32_bf16(a, bfr, acc[nt], 0, 0, 0);
        }
    }
    // epilogue: exp, bf16 stores into padded buffer, in-register row sums
    float rsum[4] = {0.f, 0.f, 0.f, 0.f};
#pragma unroll
    for (int nt = 0; nt < NTS; ++nt) {
        int n = n0 + nt * 16 + r;
        bool valid = (n < V_);
        float wgb = Wg_b[valid ? n : (V_ - 1)];
#pragma unroll
        for (int rg = 0; rg < 4; ++rg) {
            int row = w * 16 + q * 4 + rg;
            float e = valid ? __expf(acc[nt][rg] + wgb) : 0.0f;
            rsum[rg] += e;
            expg[row * PBSTR + n] = (bf16)e;   // pad region never read unguarded
        }
    }
#pragma unroll
    for (int rg = 0; rg < 4; ++rg) {
        float s = rsum[rg];
        s += __shfl_xor(s, 1);
        s += __shfl_xor(s, 2);
        s += __shfl_xor(s, 4);
        s += __shfl_xor(s, 8);
        if (r == 0) {
            int row = w * 16 + q * 4 + rg;
            pg_part[row * PSTR + blk] = s;
        }
    }
}

// K4b: proj + score_c (enc is L3-resident -> fast staging).
__global__ __launch_bounds__(256, 4) void k_proj(const float* enc, const bf16* WcPack,
                                                 const float* Wc_b, const float* dh,
                                                 const int* idxs, float* expc) {
    __shared__ unsigned char smem[34816];
    int tid = threadIdx.x;
    int w = tid >> 6, lane = tid & 63;
    int r = lane & 15, q = lane >> 4;
    int m0 = blockIdx.x * 64;
    bf16* As = (bf16*)smem;                    // 64 rows x 256 k, stride 264
    float* sred = (float*)(smem + 33792);      // 64 x 4
    f32x4 acc[16];
#pragma unroll
    for (int i = 0; i < 16; ++i) acc[i] = (f32x4){0.f, 0.f, 0.f, 0.f};
    for (int half = 0; half < 2; ++half) {
        __syncthreads();
        // two-phase staging: 16 rounds = 2 x (8 loads, 8 cvt+write)
#pragma unroll
        for (int ph = 0; ph < 2; ++ph) {
            float4 tmp[8];
#pragma unroll
            for (int j = 0; j < 8; ++j) {
                int f = (ph * 8 + j) * 256 + tid;
                int row = f >> 6, c4 = f & 63;
                tmp[j] = *(const float4*)(enc + (m0 + row) * 512 + half * 256 + c4 * 4);
            }
#pragma unroll
            for (int j = 0; j < 8; ++j) {
                int f = (ph * 8 + j) * 256 + tid;
                int row = f >> 6, c4 = f & 63;
                bf16x4 o;
                o[0] = (bf16)tmp[j].x; o[1] = (bf16)tmp[j].y;
                o[2] = (bf16)tmp[j].z; o[3] = (bf16)tmp[j].w;
                *(bf16x4*)(As + row * 264 + c4 * 4) = o;
            }
        }
        __syncthreads();
#pragma unroll
        for (int ks = 0; ks < 8; ++ks) {
            int kstep = half * 8 + ks;
            bf16x8 bfr[4];
#pragma unroll
            for (int ntl = 0; ntl < 4; ++ntl)
                bfr[ntl] = *(const bf16x8*)(WcPack + (((w * 4 + ntl) * 16 + kstep) * 64 + lane) * 8);
#pragma unroll
            for (int mt = 0; mt < 4; ++mt) {
                bf16x8 a = *(const bf16x8*)(As + (mt * 16 + r) * 264 + ks * 32 + q * 8);
#pragma unroll
                for (int ntl = 0; ntl < 4; ++ntl)
                    acc[mt * 4 + ntl] = __builtin_amdgcn_mfma_f32_16x16x32_bf16(a, bfr[ntl], acc[mt * 4 + ntl], 0, 0, 0);
            }
        }
    }
#pragma unroll
    for (int mt = 0; mt < 4; ++mt) {
#pragma unroll
        for (int rg = 0; rg < 4; ++rg) {
            int rowl = mt * 16 + q * 4 + rg;
            int row = m0 + rowl;
            int b = row / T_;
            float s = 0.0f;
#pragma unroll
            for (int ntl = 0; ntl < 4; ++ntl) {
                int n = (w * 4 + ntl) * 16 + r;
                float pv = tanh_(acc[mt * 4 + ntl][rg] + Wc_b[n]);
                s += pv * dh[b * H_ + n];
            }
            s += __shfl_xor(s, 1);
            s += __shfl_xor(s, 2);
            s += __shfl_xor(s, 4);
            s += __shfl_xor(s, 8);
            if (r == 0) sred[rowl * 4 + w] = s;
        }
    }
    __syncthreads();
    if (tid < 64) {
        float s = sred[tid * 4] + sred[tid * 4 + 1] + sred[tid * 4 + 2] + sred[tid * 4 + 3];
        int row = m0 + tid;
        int b = row / T_, t = row - b * T_;
        float sc = tanh_(s);
        if (idxs[b * T_ + t] == 0) sc -= 10000.0f;
        expc[row] = __expf(sc);
    }
}

// K5a: per-b reduction -> inv[b]; match/cf; selective_read. (proven r0/r3 form)
__global__ void k_reduce(const float* pg_part, const float* expc_, const int* idxs,
                         const int* dec, const float* enc, float* inv_out,
                         float* out_sel) {
    __shared__ float red[256];
    __shared__ float cf[256];
    int b = blockIdx.x, t = threadIdx.x;
    float s = 0.0f;
    for (int i = t; i < GSC; i += 256) s += pg_part[b * PSTR + i];
    if (t < T_) s += expc_[b * T_ + t];
    red[t] = s;
    __syncthreads();
    for (int k = 128; k > 0; k >>= 1) {
        if (t < k) red[t] += red[t + k];
        __syncthreads();
    }
    float iv = 1.0f / red[0];
    if (t == 0) inv_out[b] = iv;
    __syncthreads();
    int d = dec[b];
    float ec = 0.0f;
    int m = 0;
    if (t < T_) {
        int ix = idxs[b * T_ + t];
        ec = expc_[b * T_ + t];
        m = (ix == d) ? 1 : 0;
    }
    cf[t] = m ? ec * iv : 0.0f;
    red[t] = m ? 1.0f : 0.0f;
    __syncthreads();
    for (int k = 128; k > 0; k >>= 1) {
        if (t < k) red[t] += red[t + k];
        __syncthreads();
    }
    float tot = red[0];
    float scale = (tot > 1.0f) ? 1.0f / tot : 1.0f;
    float a0 = 0.0f, a1 = 0.0f;
    for (int tt = 0; tt < T_; ++tt) {
        float c = cf[tt];
        if (c != 0.0f) {
            float wgt = c * scale;
            a0 += wgt * enc[(b * T_ + tt) * 512 + t];
            a1 += wgt * enc[(b * T_ + tt) * 512 + t + 256];
        }
    }
    out_sel[b * 512 + t] = a0;
    out_sel[b * 512 + t + 256] = a1;
}

// K5b: streaming normalize: out_prob = expg * inv (OOV pad = 1e-4).
// 4096 blocks (128 rows x 32 chunks). Stores are ALIGNED float4 on out_prob;
// the per-row misaligned bf16 source is handled by two aligned bf16x4 loads
// + a wave-uniform shift select (sh = col&3 is constant per row).
__global__ __launch_bounds__(256) void k_normwrite(const bf16* expg, const float* inv,
                                                   float* out_prob) {
    int b = blockIdx.x >> 5, c = blockIdx.x & 31;
    int t = threadIdx.x;
    float iv = inv[b];
    int base = b * VO_;
    const bf16* eg = expg + b * PBSTR;
    int i4s = (base + 3) >> 2;            // first aligned float4 slot
    int i4e = (base + VO_) >> 2;          // end (exclusive)
    int head = (i4s << 2) - base;         // 0..3 scalar cols at row start
    if (c == 0 && t < head) {
        int col = t;                      // col < 3 << V_ always
        out_prob[base + col] = (float)eg[col] * iv;
    }
    int tail = (base + VO_) - (i4e << 2); // 0..3 scalar cols at row end
    if (c == 31 && t < tail) {
        int col = (i4e << 2) - base + t;
        out_prob[base + col] = (col < V_) ? (float)eg[col] * iv : 1e-4f;
    }
    int n4 = i4e - i4s;
    int per = (n4 + 31) >> 5;
    int s0 = i4s + c * per;
    int e0 = s0 + per; if (e0 > i4e) e0 = i4e;
    int sh = ((i4s << 2) - base) == 0 ? 0 : (4 - ((base) & 3)) & 3;  // col&3, uniform
    // (col = i4*4 - base  =>  col & 3 == (-base) & 3)
    sh = (4 - (base & 3)) & 3;
    for (int i4 = s0 + t; i4 < e0; i4 += 256) {
        int col = (i4 << 2) - base;
        int al = col & ~3;
        bf16x4 L0 = *(const bf16x4*)(eg + al);
        bf16x4 L1 = *(const bf16x4*)(eg + al + 4);
        float f0 = (float)L0[0], f1 = (float)L0[1], f2 = (float)L0[2], f3 = (float)L0[3];
        float f4 = (float)L1[0], f5 = (float)L1[1], f6 = (float)L1[2], f7 = (float)L1[3];
        float v0, v1, v2, v3;
        if (sh == 0)      { v0 = f0; v1 = f1; v2 = f2; v3 = f3; }
        else if (sh == 1) { v0 = f1; v1 = f2; v2 = f3; v3 = f4; }
        else if (sh == 2) { v0 = f2; v1 = f3; v2 = f4; v3 = f5; }
        else              { v0 = f3; v1 = f4; v2 = f5; v3 = f6; }
        float o0 = (col + 0 < V_) ? v0 * iv : 1e-4f;
        float o1 = (col + 1 < V_) ? v1 * iv : 1e-4f;
        float o2 = (col + 2 < V_) ? v2 * iv : 1e-4f;
        float o3 = (col + 3 < V_) ? v3 * iv : 1e-4f;
        *(float4*)(out_prob + (i4 << 2)) = make_float4(o0, o1, o2, o3);
    }
}

// K5c: scatter normalized copy-probs on top of the normalized base (stream-ordered
// after k_normwrite; atomics handle duplicate targets within a row).
__global__ void k_scatter(const float* expc_, const int* idxs, const float* inv,
                          float* out_prob) {
    int b = blockIdx.x, t = threadIdx.x;
    if (t < T_) {
        int ix = idxs[b * T_ + t];
        atomicAdd(&out_prob[b * VO_ + ix], expc_[b * T_ + t] * inv[b]);
    }
}

extern "C" void kernel_launch(void* const* d_in, const int* in_sizes, int n_in,
                              void* d_out, int out_size, void* d_ws, size_t ws_size,
                              hipStream_t stream) {
    const int*   dec     = (const int*)d_in[0];
    const float* enc     = (const float*)d_in[1];
    const int*   idxs    = (const int*)d_in[2];
    const float* prev    = (const float*)d_in[3];
    const float* selread = (const float*)d_in[4];
    const int*   step_p  = (const int*)d_in[5];
    const float* emb     = (const float*)d_in[6];
    const float* W_ih    = (const float*)d_in[7];
    const float* W_hh    = (const float*)d_in[8];
    const float* b_ih    = (const float*)d_in[9];
    const float* b_hh    = (const float*)d_in[10];
    const float* Wi_w    = (const float*)d_in[11];
    const float* Wi_b    = (const float*)d_in[12];
    const float* Wg_w    = (const float*)d_in[13];
    const float* Wg_b    = (const float*)d_in[14];
    const float* Wc_w    = (const float*)d_in[15];
    const float* Wc_b    = (const float*)d_in[16];

    float* ws     = (float*)d_ws;
    float* hT     = ws;                 // 32768
    float* ginT   = ws + 32768;         // 81920
    float* giT    = ws + 114688;        // 98304
    float* ghT    = ws + 212992;        // 98304
    float* inv    = ws + 311296;        // 128
    float* expc   = ws + 311552;        // 25600
    float* pgp    = ws + 337152;        // 128*800 = 102400
    bf16*  Apack  = (bf16*)(ws + 741376);   // 32768 bf16 (64KB)
    bf16*  WcPack = (bf16*)(ws + 757760);   // 131072 bf16 (256KB)
    bf16*  expg   = (bf16*)(ws + 823296);   // 128*50368 bf16 (12.9MB, padded)

    float* out      = (float*)d_out;
    float* out_prob = out;                       // 128*50307
    float* out_dh   = out + 6439296;             // 128*256
    float* out_sel  = out + 6439296 + 32768;     // 128*512
    // WgPack scratch aliases out_prob: 50304*256 bf16 = 6,438,912 floats
    // <= 6,439,296 (out_prob size). Dead once k_normwrite overwrites out_prob.
    bf16*  WgPack   = (bf16*)out;

    k_front<<<256 + GWPACK, 256, 0, stream>>>(Wc_w, WcPack, step_p, enc, prev, selread,
                                              dec, emb, Wi_w, Wi_b, hT, ginT,
                                              Wg_w, WgPack);
    k_gemm_gru<<<768, 256, 0, stream>>>(W_ih, b_ih, W_hh, b_hh, ginT, hT, giT, ghT);
    k_gru_cell<<<B_, 256, 0, stream>>>(giT, ghT, hT, out_dh, Apack);
    k_proj<<<GPJ, 256, 0, stream>>>(enc, WcPack, Wc_b, out_dh, idxs, expc);
    k_score<<<GSC, 512, 0, stream>>>(Apack, WgPack, Wg_b, expg, pgp);
    k_reduce<<<B_, 256, 0, stream>>>(pgp, expc, idxs, dec, enc, inv, out_sel);
    k_normwrite<<<B_ * 32, 256, 0, stream>>>(expg, inv, out_prob);
    k_scatter<<<B_, 256, 0, stream>>>(expc, idxs, inv, out_prob);
}

// Round 8
// 271.077 us; speedup vs baseline: 1.2872x; 1.0458x over previous
//
#include <hip/hip_runtime.h>

typedef __bf16 bf16;
typedef __bf16 bf16x4 __attribute__((ext_vector_type(4)));
typedef __bf16 bf16x8 __attribute__((ext_vector_type(8)));
typedef float f32x4 __attribute__((ext_vector_type(4)));

#define B_ 128
#define T_ 200
#define V_ 50257
#define H_ 256
#define E_ 128
#define OOV_ 50
#define VO_ 50307          // V + OOV
#define NRG 64             // n-rows per score block
#define NTS 4              // 16-wide n-tiles per score block
#define GSC 786            // score blocks (786*64 = 50304 >= V)
#define NROWP 50304        // padded Wg rows (GSC*64)
#define PSTR 800           // pg_part row stride
#define PBSTR 50368        // padded bf16 exp-buffer stride (x2B = 100736, 128B-aligned)
#define GPJ 800            // proj blocks (32 rows each; 800*32 = 25600 = B*T)

__device__ __forceinline__ float sigmoid_(float x) { return 1.0f / (1.0f + __expf(-x)); }
__device__ __forceinline__ float tanh_(float x) { return 1.0f - 2.0f / (__expf(2.0f * x) + 1.0f); }

// K1: fused front kernel.
//  blocks [0,128):        pack Wc fp32 -> bf16 frag order [nt16][ks16][lane64][8]
//  blocks [128,256):      prep (hT, ginT)
//  blocks [256,256+GSC):  pack Wg fp32 -> bf16 frag order, WAVE-CONTIGUOUS writes:
//    wave w of pack-block pb owns n-tile nt=pb*4+w; for each ks it writes one
//    contiguous fully-covered 1KB region (16B per lane) -- no partial-line RMW
//    (r7 k_proj showed 19.7MB writeback drag from the old 8B-scattered pack).
//    (WgPack lives in the out_prob region: dead until k_normwrite overwrites it)
__global__ void k_front(const float* Wc_w, bf16* WcPack,
                        const int* step_p, const float* enc, const float* prev,
                        const float* selread, const int* dec, const float* emb,
                        const float* Wi_w, const float* Wi_b,
                        float* hT, float* ginT,
                        const float* Wg_w, bf16* WgPack) {
    if (blockIdx.x < 128) {
        int gid = blockIdx.x * 256 + threadIdx.x;   // 32768 float4s
        int n = gid >> 7;
        int k = (gid & 127) * 4;
        float4 v = *(const float4*)(Wc_w + n * 512 + k);
        int kstep = k >> 5, kin = k & 31;
        int q = kin >> 3, j0 = kin & 7;
        int r = n & 15, nt = n >> 4;
        int lane = q * 16 + r;
        bf16* d = WcPack + (((nt * 16 + kstep) * 64) + lane) * 8 + j0;
        d[0] = (bf16)v.x; d[1] = (bf16)v.y; d[2] = (bf16)v.z; d[3] = (bf16)v.w;
    } else if (blockIdx.x < 256) {
        int b = blockIdx.x - 128, t = threadIdx.x;
        int step = step_p[0];
        float h;
        if (step == 0) {
            float acc = Wi_b[t];
            const float* er = enc + (b * T_ + (T_ - 1)) * 512;
            const float* wr = Wi_w + t * 512;
            for (int k = 0; k < 512; ++k) acc += er[k] * wr[k];
            h = acc;
        } else {
            h = prev[b * H_ + t];
        }
        hT[t * B_ + b] = h;
        for (int k = t; k < 512; k += 256)
            ginT[k * B_ + b] = (step == 0) ? 0.0f : selread[b * 512 + k];
        if (t < E_)
            ginT[(512 + t) * B_ + b] = emb[dec[b] * E_ + t];
    } else {
        // Wg pack, LDS-free: lane loads its own 8 source floats, stores its
        // 16B fragment slot. Pad rows (>= V_) are zeroed.
        int pb = blockIdx.x - 256;                 // 0..GSC-1
        int t = threadIdx.x;
        int w = t >> 6, lane = t & 63;
        int r = lane & 15, q = lane >> 4;
        int nt = pb * 4 + w;                       // global 16-row tile
        int row = nt * 16 + r;
        bool valid = (row < V_);
        const float* src = Wg_w + (size_t)(valid ? row : (V_ - 1)) * 256 + q * 8;
        bf16* dst = WgPack + ((size_t)(nt * 8) * 64 + lane) * 8;
#pragma unroll
        for (int ks = 0; ks < 8; ++ks) {
            float4 va = *(const float4*)(src + ks * 32);
            float4 vb = *(const float4*)(src + ks * 32 + 4);
            bf16x8 o;
            if (valid) {
                o[0] = (bf16)va.x; o[1] = (bf16)va.y; o[2] = (bf16)va.z; o[3] = (bf16)va.w;
                o[4] = (bf16)vb.x; o[5] = (bf16)vb.y; o[6] = (bf16)vb.z; o[7] = (bf16)vb.w;
            } else {
                o[0] = o[1] = o[2] = o[3] = o[4] = o[5] = o[6] = o[7] = (bf16)0.0f;
            }
            *(bf16x8*)(dst + (size_t)ks * 512) = o;   // wave-contiguous 1KB/(nt,ks)
        }
    }
}

// K2: gi = gru_in @ W_ih^T + b_ih ; gh = h @ W_hh^T + b_hh  (K-split, 768 blocks)
__global__ void k_gemm_gru(const float* W_ih, const float* b_ih,
                           const float* W_hh, const float* b_hh,
                           const float* ginT, const float* hT,
                           float* giT, float* ghT) {
    __shared__ float red[256];
    int rrow = blockIdx.x;            // 0..767
    int t = threadIdx.x;
    int b = t & 127, kh = t >> 7;
    const float* w = W_ih + rrow * 640 + kh * 320;
    const float* g = ginT + (kh * 320) * B_ + b;
    float a0 = 0.f, a1 = 0.f, a2 = 0.f, a3 = 0.f;
#pragma unroll 4
    for (int k = 0; k < 320; k += 4) {
        a0 += w[k]     * g[k * B_];
        a1 += w[k + 1] * g[(k + 1) * B_];
        a2 += w[k + 2] * g[(k + 2) * B_];
        a3 += w[k + 3] * g[(k + 3) * B_];
    }
    const float* w2 = W_hh + rrow * 256 + kh * 128;
    const float* hh = hT + (kh * 128) * B_ + b;
    float c0 = 0.f, c1 = 0.f, c2 = 0.f, c3 = 0.f;
#pragma unroll 4
    for (int k = 0; k < 128; k += 4) {
        c0 += w2[k]     * hh[k * B_];
        c1 += w2[k + 1] * hh[(k + 1) * B_];
        c2 += w2[k + 2] * hh[(k + 2) * B_];
        c3 += w2[k + 3] * hh[(k + 3) * B_];
    }
    red[t] = ((a0 + a1) + (a2 + a3));
    __syncthreads();
    if (kh == 0) giT[rrow * B_ + b] = b_ih[rrow] + red[b] + red[b + 128];
    __syncthreads();
    red[t] = ((c0 + c1) + (c2 + c3));
    __syncthreads();
    if (kh == 0) ghT[rrow * B_ + b] = b_hh[rrow] + red[b] + red[b + 128];
}

// K3: GRU cell -> decode_hidden fp32 (out) + bf16 A-fragment-packed copy
__global__ void k_gru_cell(const float* giT, const float* ghT, const float* hT,
                           float* out_dh, bf16* Apack) {
    int b = blockIdx.x, j = threadIdx.x;
    float ir = giT[j * B_ + b], iz = giT[(256 + j) * B_ + b], in_ = giT[(512 + j) * B_ + b];
    float hr = ghT[j * B_ + b], hz = ghT[(256 + j) * B_ + b], hn = ghT[(512 + j) * B_ + b];
    float hp = hT[j * B_ + b];
    float r = sigmoid_(ir + hr);
    float z = sigmoid_(iz + hz);
    float n = tanh_(in_ + r * hn);
    float h = (1.0f - z) * n + z * hp;
    out_dh[b * H_ + j] = h;
    // Apack[mt(8)][ks(8)][lane(64)][8]: m = mt*16 + (lane&15), k = ks*32 + (lane>>4)*8 + jj
    int mt = b >> 4, rr = b & 15, ks = j >> 5, q = (j >> 3) & 3, jj = j & 7;
    Apack[(((mt * 8 + ks) * 64) + (q * 16 + rr)) * 8 + jj] = (bf16)h;
}

// K4a: score_g. 512 threads / 8 waves, wave w owns m-tile w. B-fragments are
// DIRECT bf16x8 loads from fragment-ordered WgPack (load IS the MFMA operand).
__global__ __launch_bounds__(512, 2) void k_score(const bf16* Apack, const bf16* WgPack,
                                                  const float* Wg_b,
                                                  bf16* expg, float* pg_part) {
    int tid = threadIdx.x;
    int w = tid >> 6, lane = tid & 63;
    int r = lane & 15, q = lane >> 4;
    int blk = blockIdx.x;
    int n0 = blk * NRG;
    const bf16* bbase = WgPack + (size_t)(blk * NTS * 8) * 512 + lane * 8;
    const bf16* abase = Apack + (w * 8) * 512 + lane * 8;
    f32x4 acc[NTS];
#pragma unroll
    for (int i = 0; i < NTS; ++i) acc[i] = (f32x4){0.f, 0.f, 0.f, 0.f};
#pragma unroll
    for (int ks = 0; ks < 8; ++ks) {
        bf16x8 a = *(const bf16x8*)(abase + ks * 512);
#pragma unroll
        for (int nt = 0; nt < NTS; ++nt) {
            bf16x8 bfr = *(const bf16x8*)(bbase + (nt * 8 + ks) * 512);
            acc[nt] = __builtin_amdgcn_mfma_f32_16x16x32_bf16(a, bfr, acc[nt], 0, 0, 0);
        }
    }
    // epilogue: exp, bf16 stores into padded buffer, in-register row sums
    float rsum[4] = {0.f, 0.f, 0.f, 0.f};
#pragma unroll
    for (int nt = 0; nt < NTS; ++nt) {
        int n = n0 + nt * 16 + r;
        bool valid = (n < V_);
        float wgb = Wg_b[valid ? n : (V_ - 1)];
#pragma unroll
        for (int rg = 0; rg < 4; ++rg) {
            int row = w * 16 + q * 4 + rg;
            float e = valid ? __expf(acc[nt][rg] + wgb) : 0.0f;
            rsum[rg] += e;
            expg[row * PBSTR + n] = (bf16)e;   // pad region never read unguarded
        }
    }
#pragma unroll
    for (int rg = 0; rg < 4; ++rg) {
        float s = rsum[rg];
        s += __shfl_xor(s, 1);
        s += __shfl_xor(s, 2);
        s += __shfl_xor(s, 4);
        s += __shfl_xor(s, 8);
        if (r == 0) {
            int row = w * 16 + q * 4 + rg;
            pg_part[row * PSTR + blk] = s;
        }
    }
}

// K4b: proj + score_c. 32 rows/block (grid 800): 2x the resident blocks of r7's
// 64-row version (occupancy was 14% -> latency-bound). LDS 17.4KB, 4 blocks/CU.
__global__ __launch_bounds__(256, 4) void k_proj(const float* enc, const bf16* WcPack,
                                                 const float* Wc_b, const float* dh,
                                                 const int* idxs, float* expc) {
    __shared__ unsigned char smem[17408];
    int tid = threadIdx.x;
    int w = tid >> 6, lane = tid & 63;
    int r = lane & 15, q = lane >> 4;
    int m0 = blockIdx.x * 32;
    bf16* As = (bf16*)smem;                    // 32 rows x 256 k, stride 264
    float* sred = (float*)(smem + 16896);      // 32 x 4
    f32x4 acc[8];
#pragma unroll
    for (int i = 0; i < 8; ++i) acc[i] = (f32x4){0.f, 0.f, 0.f, 0.f};
    for (int half = 0; half < 2; ++half) {
        __syncthreads();
        // two-phase staging: 8 rounds = 2 x (4 loads, 4 cvt+write)
#pragma unroll
        for (int ph = 0; ph < 2; ++ph) {
            float4 tmp[4];
#pragma unroll
            for (int j = 0; j < 4; ++j) {
                int f = (ph * 4 + j) * 256 + tid;   // 2048 float4s
                int row = f >> 6, c4 = f & 63;
                tmp[j] = *(const float4*)(enc + (m0 + row) * 512 + half * 256 + c4 * 4);
            }
#pragma unroll
            for (int j = 0; j < 4; ++j) {
                int f = (ph * 4 + j) * 256 + tid;
                int row = f >> 6, c4 = f & 63;
                bf16x4 o;
                o[0] = (bf16)tmp[j].x; o[1] = (bf16)tmp[j].y;
                o[2] = (bf16)tmp[j].z; o[3] = (bf16)tmp[j].w;
                *(bf16x4*)(As + row * 264 + c4 * 4) = o;
            }
        }
        __syncthreads();
#pragma unroll
        for (int ks = 0; ks < 8; ++ks) {
            int kstep = half * 8 + ks;
            bf16x8 bfr[4];
#pragma unroll
            for (int ntl = 0; ntl < 4; ++ntl)
                bfr[ntl] = *(const bf16x8*)(WcPack + (((w * 4 + ntl) * 16 + kstep) * 64 + lane) * 8);
#pragma unroll
            for (int mt = 0; mt < 2; ++mt) {
                bf16x8 a = *(const bf16x8*)(As + (mt * 16 + r) * 264 + ks * 32 + q * 8);
#pragma unroll
                for (int ntl = 0; ntl < 4; ++ntl)
                    acc[mt * 4 + ntl] = __builtin_amdgcn_mfma_f32_16x16x32_bf16(a, bfr[ntl], acc[mt * 4 + ntl], 0, 0, 0);
            }
        }
    }
#pragma unroll
    for (int mt = 0; mt < 2; ++mt) {
#pragma unroll
        for (int rg = 0; rg < 4; ++rg) {
            int rowl = mt * 16 + q * 4 + rg;
            int row = m0 + rowl;
            int b = row / T_;
            float s = 0.0f;
#pragma unroll
            for (int ntl = 0; ntl < 4; ++ntl) {
                int n = (w * 4 + ntl) * 16 + r;
                float pv = tanh_(acc[mt * 4 + ntl][rg] + Wc_b[n]);
                s += pv * dh[b * H_ + n];
            }
            s += __shfl_xor(s, 1);
            s += __shfl_xor(s, 2);
            s += __shfl_xor(s, 4);
            s += __shfl_xor(s, 8);
            if (r == 0) sred[rowl * 4 + w] = s;
        }
    }
    __syncthreads();
    if (tid < 32) {
        float s = sred[tid * 4] + sred[tid * 4 + 1] + sred[tid * 4 + 2] + sred[tid * 4 + 3];
        int row = m0 + tid;
        int b = row / T_, t = row - b * T_;
        float sc = tanh_(s);
        if (idxs[b * T_ + t] == 0) sc -= 10000.0f;
        expc[row] = __expf(sc);
    }
}

// K5a: per-b reduction -> inv[b]; match/cf; selective_read. (proven r0/r3 form)
__global__ void k_reduce(const float* pg_part, const float* expc_, const int* idxs,
                         const int* dec, const float* enc, float* inv_out,
                         float* out_sel) {
    __shared__ float red[256];
    __shared__ float cf[256];
    int b = blockIdx.x, t = threadIdx.x;
    float s = 0.0f;
    for (int i = t; i < GSC; i += 256) s += pg_part[b * PSTR + i];
    if (t < T_) s += expc_[b * T_ + t];
    red[t] = s;
    __syncthreads();
    for (int k = 128; k > 0; k >>= 1) {
        if (t < k) red[t] += red[t + k];
        __syncthreads();
    }
    float iv = 1.0f / red[0];
    if (t == 0) inv_out[b] = iv;
    __syncthreads();
    int d = dec[b];
    float ec = 0.0f;
    int m = 0;
    if (t < T_) {
        int ix = idxs[b * T_ + t];
        ec = expc_[b * T_ + t];
        m = (ix == d) ? 1 : 0;
    }
    cf[t] = m ? ec * iv : 0.0f;
    red[t] = m ? 1.0f : 0.0f;
    __syncthreads();
    for (int k = 128; k > 0; k >>= 1) {
        if (t < k) red[t] += red[t + k];
        __syncthreads();
    }
    float tot = red[0];
    float scale = (tot > 1.0f) ? 1.0f / tot : 1.0f;
    float a0 = 0.0f, a1 = 0.0f;
    for (int tt = 0; tt < T_; ++tt) {
        float c = cf[tt];
        if (c != 0.0f) {
            float wgt = c * scale;
            a0 += wgt * enc[(b * T_ + tt) * 512 + t];
            a1 += wgt * enc[(b * T_ + tt) * 512 + t + 256];
        }
    }
    out_sel[b * 512 + t] = a0;
    out_sel[b * 512 + t + 256] = a1;
}

// K5b: streaming normalize: out_prob = expg * inv (OOV pad = 1e-4).
// 4096 blocks (128 rows x 32 chunks). Aligned float4 stores; misaligned bf16
// source via two aligned bf16x4 loads + wave-uniform shift select.
__global__ __launch_bounds__(256) void k_normwrite(const bf16* expg, const float* inv,
                                                   float* out_prob) {
    int b = blockIdx.x >> 5, c = blockIdx.x & 31;
    int t = threadIdx.x;
    float iv = inv[b];
    int base = b * VO_;
    const bf16* eg = expg + b * PBSTR;
    int i4s = (base + 3) >> 2;            // first aligned float4 slot
    int i4e = (base + VO_) >> 2;          // end (exclusive)
    int head = (i4s << 2) - base;         // 0..3 scalar cols at row start
    if (c == 0 && t < head) {
        int col = t;
        out_prob[base + col] = (float)eg[col] * iv;
    }
    int tail = (base + VO_) - (i4e << 2); // 0..3 scalar cols at row end
    if (c == 31 && t < tail) {
        int col = (i4e << 2) - base + t;
        out_prob[base + col] = (col < V_) ? (float)eg[col] * iv : 1e-4f;
    }
    int n4 = i4e - i4s;
    int per = (n4 + 31) >> 5;
    int s0 = i4s + c * per;
    int e0 = s0 + per; if (e0 > i4e) e0 = i4e;
    int sh = (4 - (base & 3)) & 3;        // col&3, uniform per row
    for (int i4 = s0 + t; i4 < e0; i4 += 256) {
        int col = (i4 << 2) - base;
        int al = col & ~3;
        bf16x4 L0 = *(const bf16x4*)(eg + al);
        bf16x4 L1 = *(const bf16x4*)(eg + al + 4);
        float f0 = (float)L0[0], f1 = (float)L0[1], f2 = (float)L0[2], f3 = (float)L0[3];
        float f4 = (float)L1[0], f5 = (float)L1[1], f6 = (float)L1[2];
        float v0, v1, v2, v3;
        if (sh == 0)      { v0 = f0; v1 = f1; v2 = f2; v3 = f3; }
        else if (sh == 1) { v0 = f1; v1 = f2; v2 = f3; v3 = f4; }
        else if (sh == 2) { v0 = f2; v1 = f3; v2 = f4; v3 = f5; }
        else              { v0 = f3; v1 = f4; v2 = f5; v3 = f6; }
        float o0 = (col + 0 < V_) ? v0 * iv : 1e-4f;
        float o1 = (col + 1 < V_) ? v1 * iv : 1e-4f;
        float o2 = (col + 2 < V_) ? v2 * iv : 1e-4f;
        float o3 = (col + 3 < V_) ? v3 * iv : 1e-4f;
        *(float4*)(out_prob + (i4 << 2)) = make_float4(o0, o1, o2, o3);
    }
}

// K5c: scatter normalized copy-probs on top of the normalized base.
__global__ void k_scatter(const float* expc_, const int* idxs, const float* inv,
                          float* out_prob) {
    int b = blockIdx.x, t = threadIdx.x;
    if (t < T_) {
        int ix = idxs[b * T_ + t];
        atomicAdd(&out_prob[b * VO_ + ix], expc_[b * T_ + t] * inv[b]);
    }
}

extern "C" void kernel_launch(void* const* d_in, const int* in_sizes, int n_in,
                              void* d_out, int out_size, void* d_ws, size_t ws_size,
                              hipStream_t stream) {
    const int*   dec     = (const int*)d_in[0];
    const float* enc     = (const float*)d_in[1];
    const int*   idxs    = (const int*)d_in[2];
    const float* prev    = (const float*)d_in[3];
    const float* selread = (const float*)d_in[4];
    const int*   step_p  = (const int*)d_in[5];
    const float* emb     = (const float*)d_in[6];
    const float* W_ih    = (const float*)d_in[7];
    const float* W_hh    = (const float*)d_in[8];
    const float* b_ih    = (const float*)d_in[9];
    const float* b_hh    = (const float*)d_in[10];
    const float* Wi_w    = (const float*)d_in[11];
    const float* Wi_b    = (const float*)d_in[12];
    const float* Wg_w    = (const float*)d_in[13];
    const float* Wg_b    = (const float*)d_in[14];
    const float* Wc_w    = (const float*)d_in[15];
    const float* Wc_b    = (const float*)d_in[16];

    float* ws     = (float*)d_ws;
    float* hT     = ws;                 // 32768
    float* ginT   = ws + 32768;         // 81920
    float* giT    = ws + 114688;        // 98304
    float* ghT    = ws + 212992;        // 98304
    float* inv    = ws + 311296;        // 128
    float* expc   = ws + 311552;        // 25600
    float* pgp    = ws + 337152;        // 128*800 = 102400
    bf16*  Apack  = (bf16*)(ws + 741376);   // 32768 bf16 (64KB)
    bf16*  WcPack = (bf16*)(ws + 757760);   // 131072 bf16 (256KB)
    bf16*  expg   = (bf16*)(ws + 823296);   // 128*50368 bf16 (12.9MB, padded)

    float* out      = (float*)d_out;
    float* out_prob = out;                       // 128*50307
    float* out_dh   = out + 6439296;             // 128*256
    float* out_sel  = out + 6439296 + 32768;     // 128*512
    // WgPack scratch aliases out_prob: 50304*256 bf16 = 6,438,912 floats
    // <= 6,439,296 (out_prob size). Dead once k_normwrite overwrites out_prob.
    bf16*  WgPack   = (bf16*)out;

    k_front<<<256 + GSC, 256, 0, stream>>>(Wc_w, WcPack, step_p, enc, prev, selread,
                                           dec, emb, Wi_w, Wi_b, hT, ginT,
                                           Wg_w, WgPack);
    k_gemm_gru<<<768, 256, 0, stream>>>(W_ih, b_ih, W_hh, b_hh, ginT, hT, giT, ghT);
    k_gru_cell<<<B_, 256, 0, stream>>>(giT, ghT, hT, out_dh, Apack);
    k_proj<<<GPJ, 256, 0, stream>>>(enc, WcPack, Wc_b, out_dh, idxs, expc);
    k_score<<<GSC, 512, 0, stream>>>(Apack, WgPack, Wg_b, expg, pgp);
    k_reduce<<<B_, 256, 0, stream>>>(pgp, expc, idxs, dec, enc, inv, out_sel);
    k_normwrite<<<B_ * 32, 256, 0, stream>>>(expg, inv, out_prob);
    k_scatter<<<B_, 256, 0, stream>>>(expc, idxs, inv, out_prob);
}